// Round 1
// baseline (389.093 us; speedup 1.0000x reference)
//
#include <hip/hip_runtime.h>
#include <hip/hip_bf16.h>
#include <hip/hip_fp16.h>

#define B_ 2
#define S_ 2048
#define D_ 2048
#define H_ 8
#define KV_ 2
#define HD_ 256
#define WINDOW_ 512
#define EPS_ 1e-6f
#define MASKV_ -30000.0f

typedef _Float16 f16;
typedef _Float16 half8 __attribute__((ext_vector_type(8)));
typedef _Float16 half2v __attribute__((ext_vector_type(2)));
typedef _Float16 half4v __attribute__((ext_vector_type(4)));
typedef float floatx4 __attribute__((ext_vector_type(4)));
typedef float floatx8 __attribute__((ext_vector_type(8)));
typedef float floatx16 __attribute__((ext_vector_type(16)));

#define GLOAD_LDS16(g, l)                                                        \
    __builtin_amdgcn_global_load_lds(                                            \
        (const __attribute__((address_space(1))) unsigned int*)(g),              \
        (__attribute__((address_space(3))) unsigned int*)(l), 16, 0, 0)

// ---------------------------------------------------------------------------
// prep: fp32->fp16 convert of x + all 4 weight transposes (64x64 tiles,
// half4 dst writes -> 128B contiguous store segments).  (unchanged)
// ---------------------------------------------------------------------------
__global__ __launch_bounds__(256) void prep(const float* __restrict__ x,
                                            const float* __restrict__ wq,
                                            const float* __restrict__ wk,
                                            const float* __restrict__ wv,
                                            const float* __restrict__ wo,
                                            f16* __restrict__ xh,
                                            f16* __restrict__ BT,
                                            f16* __restrict__ woT) {
    int bid = blockIdx.x;
    const int t = threadIdx.x;
    if (bid < 8192) {
        const int i = bid * 256 + t;
        float4 v = ((const float4*)x)[i];
        half4v hv = {(f16)v.x, (f16)v.y, (f16)v.z, (f16)v.w};
        ((half4v*)xh)[i] = hv;
        return;
    }
    bid -= 8192;
    const float* src;
    f16* dst;
    int C, bx, by;
    if (bid < 1024) {
        src = wq; dst = BT; C = 2048; bx = bid & 31; by = bid >> 5;
    } else if (bid < 1280) {
        const int b3 = bid - 1024;
        src = wk; dst = BT + (size_t)2048 * 2048; C = 512; bx = b3 & 7; by = b3 >> 3;
    } else if (bid < 1536) {
        const int b3 = bid - 1280;
        src = wv; dst = BT + (size_t)2560 * 2048; C = 512; bx = b3 & 7; by = b3 >> 3;
    } else {
        const int b3 = bid - 1536;
        src = wo; dst = woT; C = 2048; bx = b3 & 31; by = b3 >> 5;
    }
    __shared__ float tl[64][65];
    const int c0 = bx * 64, r0 = by * 64;
#pragma unroll
    for (int i = 0; i < 4; ++i) {
        const int idx = i * 256 + t;
        const int row = idx >> 4;
        const int c4 = (idx & 15) * 4;
        float4 v = *(const float4*)&src[(size_t)(r0 + row) * C + c0 + c4];
        tl[row][c4 + 0] = v.x; tl[row][c4 + 1] = v.y;
        tl[row][c4 + 2] = v.z; tl[row][c4 + 3] = v.w;
    }
    __syncthreads();
#pragma unroll
    for (int i = 0; i < 4; ++i) {
        const int idx = i * 256 + t;
        const int c = idx >> 4;
        const int r4 = (idx & 15) * 4;
        half4v hv = {(f16)tl[r4 + 0][c], (f16)tl[r4 + 1][c],
                     (f16)tl[r4 + 2][c], (f16)tl[r4 + 3][c]};
        *(half4v*)&dst[(size_t)(c0 + c) * 2048 + r0 + r4] = hv;
    }
}

// ---------------------------------------------------------------------------
// Ring-pipelined fp16 MFMA GEMM: C[M,N] = A[M,K] @ BT[N,K]^T.
//   BM=256, BK=32, ring of 3 LDS buffers, counted vmcnt (T4), raw s_barrier,
//   setprio around MFMA cluster (T5).  32x32x16 MFMA, per-wave output 128x64.
//
// Ring invariant: tile t is read from buf t%3 while tile t+1's DMA writes land
// in (t+1)%3 and tile t+2's loads are issued into (t+2)%3 -- all distinct, so
// ONE barrier + ONE counted vmcnt per K-tile is race-free, and tile t+1's
// loads stay in flight across the wait (never vmcnt(0) in steady state).
//
// LDS layout: chunk = 8 rows x 32 k (512 B, 32 slots of 16 B).
//   slot(r,g) = g*8 + ((r&7)^g)   (g = k-group of 8 f16)
// Stage writes are linear (gload_lds dst = base + lane*16); the source global
// address is pre-swizzled per lane (both-sides-or-neither).  Fragment reads
// (row ra, group G): bank-group = 4*((ra&7)^G) -> 8 distinct per 8-row chunk,
// 2-way per 16-lane quad = conflict-free (m136).
// A/B frag: m(n)=lane&31, k=(lane>>5)*8+j.  C/D: col=lane&31,
// row=(reg&3)+8*(reg>>2)+4*(lane>>5)  [m74/m101-verified].
// ---------------------------------------------------------------------------
template <int BN, int NW, typename OutT>
__global__ __launch_bounds__(NW * 64, 2) void gemm_ring(const f16* __restrict__ A,
                                                        const f16* __restrict__ BT,
                                                        OutT* __restrict__ C,
                                                        int M, int N, int K) {
    constexpr int ASZ = 8192;            // 256 rows * 32 k (f16)
    constexpr int BSZ = BN * 32;
    constexpr int LA = 16 / NW;          // A wave-loads per wave per tile
    constexpr int LB = (BN / 16) / NW;   // B wave-loads per wave per tile
    constexpr int VM = LA + LB;          // loads in flight per future tile

    __shared__ __align__(16) f16 sA[3 * ASZ];
    __shared__ __align__(16) f16 sB[3 * BSZ];

    const int tid = threadIdx.x;
    const int lane = tid & 63, w = tid >> 6;
    const int l31 = lane & 31, q1 = lane >> 5;
    const int m0 = blockIdx.y * 256, n0 = blockIdx.x * BN;
    const int mw = (w & 1) * 128;
    const int nw = (w >> 1) * 64;

    // staging decode: slot s = lane&31 -> (g = s>>3, r7 = (s&7)^g)
    const int sg = (lane >> 3) & 3;
    const int sr7 = (lane & 7) ^ sg;
    const int halfc = lane >> 5;         // which chunk of the wave's 1KB pair

    const f16* srcA[LA];
    f16* dstA[LA];
#pragma unroll
    for (int i = 0; i < LA; ++i) {
        const int pair = w * LA + i;
        const int row = (pair * 2 + halfc) * 8 + sr7;
        srcA[i] = A + (size_t)(m0 + row) * K + sg * 8;
        dstA[i] = sA + pair * 512 + lane * 8;
    }
    const f16* srcB[LB];
    f16* dstB[LB];
#pragma unroll
    for (int i = 0; i < LB; ++i) {
        const int pair = w * LB + i;
        const int row = (pair * 2 + halfc) * 8 + sr7;
        srcB[i] = BT + (size_t)(n0 + row) * K + sg * 8;
        dstB[i] = sB + pair * 512 + lane * 8;
    }

    auto stage = [&](int tile, int buf) {
        const int ko = tile * 32;
#pragma unroll
        for (int i = 0; i < LA; ++i)
            GLOAD_LDS16(srcA[i] + ko, dstA[i] + buf * ASZ);
#pragma unroll
        for (int i = 0; i < LB; ++i)
            GLOAD_LDS16(srcB[i] + ko, dstB[i] + buf * BSZ);
    };

    // fragment-read LDS offsets (f16 units)
    const int arow = (l31 >> 3) * 256;
    const int G0 = q1;
    const int G1 = q1 + 2;
    const int X0 = G0 * 8 + ((l31 & 7) ^ G0);
    const int X1 = G1 * 8 + ((l31 & 7) ^ G1);
    const int aoff0 = (mw >> 3) * 256 + arow + X0 * 8;
    const int aoff1 = (mw >> 3) * 256 + arow + X1 * 8;
    const int boff0 = (nw >> 3) * 256 + arow + X0 * 8;
    const int boff1 = (nw >> 3) * 256 + arow + X1 * 8;

    floatx16 acc[8];
#pragma unroll
    for (int i = 0; i < 8; ++i) acc[i] = (floatx16)(0.f);

    const int NT = K >> 5;  // K / 32
    stage(0, 0);
    stage(1, 1);

    int bsel = 0;
    for (int t = 0; t < NT; ++t) {
        if (t == NT - 1) {
            asm volatile("s_waitcnt vmcnt(0)\n\ts_barrier" ::: "memory");
        } else {
            if constexpr (VM == 4)
                asm volatile("s_waitcnt vmcnt(4)\n\ts_barrier" ::: "memory");
            else
                asm volatile("s_waitcnt vmcnt(6)\n\ts_barrier" ::: "memory");
        }
        const int b2 = bsel >= 1 ? bsel - 1 : 2;   // (bsel+2)%3
        if (t + 2 < NT) stage(t + 2, b2);

        const f16* Ab = sA + bsel * ASZ;
        const f16* Bb = sB + bsel * BSZ;
        half8 a0[4], a1[4], b0[2], b1[2];
#pragma unroll
        for (int m = 0; m < 4; ++m) {
            a0[m] = *(const half8*)(Ab + aoff0 + m * 1024);
            a1[m] = *(const half8*)(Ab + aoff1 + m * 1024);
        }
#pragma unroll
        for (int n = 0; n < 2; ++n) {
            b0[n] = *(const half8*)(Bb + boff0 + n * 1024);
            b1[n] = *(const half8*)(Bb + boff1 + n * 1024);
        }
        __builtin_amdgcn_s_setprio(1);
#pragma unroll
        for (int m = 0; m < 4; ++m)
#pragma unroll
            for (int n = 0; n < 2; ++n)
                acc[m * 2 + n] = __builtin_amdgcn_mfma_f32_32x32x16_f16(
                    a0[m], b0[n], acc[m * 2 + n], 0, 0, 0);
#pragma unroll
        for (int m = 0; m < 4; ++m)
#pragma unroll
            for (int n = 0; n < 2; ++n)
                acc[m * 2 + n] = __builtin_amdgcn_mfma_f32_32x32x16_f16(
                    a1[m], b1[n], acc[m * 2 + n], 0, 0, 0);
        __builtin_amdgcn_s_setprio(0);

        bsel = bsel == 2 ? 0 : bsel + 1;
    }

#pragma unroll
    for (int m = 0; m < 4; ++m)
#pragma unroll
        for (int n = 0; n < 2; ++n)
#pragma unroll
            for (int r = 0; r < 16; ++r) {
                const int row = m0 + mw + m * 32 + (r & 3) + 8 * (r >> 2) + 4 * q1;
                const int col = n0 + nw + n * 32 + l31;
                C[(size_t)row * N + col] = (OutT)acc[m * 2 + n][r];
            }
}

// ---------------------------------------------------------------------------
// K/V norm kernel (Q handled in attn prologue).  (unchanged)
// ---------------------------------------------------------------------------
#define NRBK_ ((B_ * S_ * KV_) / 4)  // 2048 blocks, 4 waves each

__global__ __launch_bounds__(256) void norm_kv_f16(
    const f16* __restrict__ QKVh, f16* __restrict__ Kh, f16* __restrict__ Vt,
    const float* __restrict__ cosb, const float* __restrict__ sinb,
    const float* __restrict__ kw) {
    __shared__ f16 vt[64][266];

    const int w = threadIdx.x >> 6, lane = threadIdx.x & 63;

    if (blockIdx.x < NRBK_) {
        const int wid = blockIdx.x * 4 + w;   // 0..8191
        const int d0 = lane * 2;
        const int b = wid / (S_ * KV_);
        const int r = wid % (S_ * KV_);
        const int s = r / KV_, kv = r % KV_;
        const f16* p = QKVh + (size_t)(b * S_ + s) * 3072 + 2048 + kv * HD_;
        half2v lo = *(const half2v*)(p + d0);
        half2v hi = *(const half2v*)(p + 128 + d0);
        float x0 = (float)lo[0], x1 = (float)lo[1], x2 = (float)hi[0], x3 = (float)hi[1];
        float ss = x0 * x0 + x1 * x1 + x2 * x2 + x3 * x3;
#pragma unroll
        for (int off = 32; off >= 1; off >>= 1) ss += __shfl_xor(ss, off);
        const float inv = rsqrtf(ss * (1.0f / HD_) + EPS_);
        float2 wlo = *(const float2*)(kw + d0), whi = *(const float2*)(kw + 128 + d0);
        float y0 = x0 * inv * wlo.x, y1 = x1 * inv * wlo.y;
        float y2 = x2 * inv * whi.x, y3 = x3 * inv * whi.y;
        const float* cb = cosb + (size_t)(b * S_ + s) * HD_;
        const float* sb = sinb + (size_t)(b * S_ + s) * HD_;
        float2 clo = *(const float2*)(cb + d0), chi = *(const float2*)(cb + 128 + d0);
        float2 slo = *(const float2*)(sb + d0), shi = *(const float2*)(sb + 128 + d0);
        half2v olo = {(f16)(y0 * clo.x - y2 * slo.x), (f16)(y1 * clo.y - y3 * slo.y)};
        half2v ohi = {(f16)(y2 * chi.x + y0 * shi.x), (f16)(y3 * chi.y + y1 * shi.y)};
        f16* d = Kh + ((size_t)(b * KV_ + kv) * S_ + s) * HD_;
        *(half2v*)(d + d0) = olo;
        *(half2v*)(d + 128 + d0) = ohi;
        return;
    }

    const int vb = blockIdx.x - NRBK_;         // 0..127
    const int s0 = (vb & 31) * 64;
    const int kv = (vb >> 5) & 1;
    const int b  = vb >> 6;

    for (int r = 0; r < 16; ++r) {
        const int sl = w * 16 + r;
        const f16* p = QKVh + (size_t)(b * S_ + s0 + sl) * 3072 + 2560 + kv * HD_;
        const int d0 = lane * 2;
        half2v lo = *(const half2v*)(p + d0);
        half2v hi = *(const half2v*)(p + 128 + d0);
        float x0 = (float)lo[0], x1 = (float)lo[1], x2 = (float)hi[0], x3 = (float)hi[1];
        float ss = x0 * x0 + x1 * x1 + x2 * x2 + x3 * x3;
#pragma unroll
        for (int off = 32; off >= 1; off >>= 1) ss += __shfl_xor(ss, off);
        const float inv = rsqrtf(ss * (1.0f / HD_) + EPS_);
        half2v olo = {(f16)(x0 * inv), (f16)(x1 * inv)};
        half2v ohi = {(f16)(x2 * inv), (f16)(x3 * inv)};
        *(half2v*)&vt[sl][d0] = olo;
        *(half2v*)&vt[sl][128 + d0] = ohi;
    }
    __syncthreads();
    f16* dst = Vt + (size_t)(b * KV_ + kv) * HD_ * S_;
    for (int i = 0; i < 64; ++i) {
        const int dd = w * 64 + i;
        dst[(size_t)dd * S_ + s0 + lane] = vt[lane][dd];
    }
}

// ---------------------------------------------------------------------------
// MFMA flash attention (unchanged). 128 q, 8 waves, dbuf staging.
// ---------------------------------------------------------------------------
__global__ __launch_bounds__(512, 2) void attn_mfma(const f16* __restrict__ QKVh,
                                                    const f16* __restrict__ Kh,
                                                    const f16* __restrict__ Vt,
                                                    f16* __restrict__ attnh,
                                                    const float* __restrict__ cosb,
                                                    const float* __restrict__ sinb,
                                                    const float* __restrict__ qw) {
    __shared__ __align__(16) f16 sK[2][64 * 256];
    __shared__ __align__(16) f16 sV[2][256 * 64];
    __shared__ __align__(16) f16 sP[8][16 * 72];

    const int qt = blockIdx.x, h = blockIdx.y, b = blockIdx.z;
    const int kvh = h / (H_ / KV_);
    const int t = threadIdx.x, lane = t & 63, w = t >> 6;
    const int i16 = lane & 15, q4 = lane >> 4;

    const int qrow = qt * 128 + w * 16 + i16;
    const f16* qbase = QKVh + (size_t)(b * S_ + qrow) * 3072 + h * HD_ + q4 * 8;
    half8 qf[8];
#pragma unroll
    for (int kk = 0; kk < 8; ++kk) qf[kk] = *(const half8*)(qbase + kk * 32);

    {
        float ss = 0.f;
#pragma unroll
        for (int kk = 0; kk < 8; ++kk)
#pragma unroll
            for (int j = 0; j < 8; ++j) {
                const float v = (float)qf[kk][j];
                ss += v * v;
            }
        ss += __shfl_xor(ss, 16);
        ss += __shfl_xor(ss, 32);
        const float inv = rsqrtf(ss * (1.0f / HD_) + EPS_);
        const float* cb = cosb + (size_t)(b * S_ + qrow) * HD_ + q4 * 8;
        const float* sb = sinb + (size_t)(b * S_ + qrow) * HD_ + q4 * 8;
        const float* wp = qw + q4 * 8;
#pragma unroll
        for (int kk = 0; kk < 4; ++kk) {
            const int dl = kk * 32, dh = dl + 128;
            floatx8 cl = *(const floatx8*)(cb + dl);
            floatx8 ch = *(const floatx8*)(cb + dh);
            floatx8 sl = *(const floatx8*)(sb + dl);
            floatx8 sh = *(const floatx8*)(sb + dh);
            floatx8 wl = *(const floatx8*)(wp + dl);
            floatx8 wh = *(const floatx8*)(wp + dh);
            half8 nl, nh;
#pragma unroll
            for (int j = 0; j < 8; ++j) {
                const float xl = (float)qf[kk][j] * inv * wl[j];
                const float xh = (float)qf[kk + 4][j] * inv * wh[j];
                nl[j] = (f16)(xl * cl[j] - xh * sl[j]);
                nh[j] = (f16)(xh * ch[j] + xl * sh[j]);
            }
            qf[kk] = nl;
            qf[kk + 4] = nh;
        }
    }

    floatx4 o[16];
#pragma unroll
    for (int i = 0; i < 16; ++i) o[i] = (floatx4){0.f, 0.f, 0.f, 0.f};
    float mrow[4] = {-1e30f, -1e30f, -1e30f, -1e30f};
    float lrow[4] = {0.f, 0.f, 0.f, 0.f};

    const size_t kbase = (size_t)(b * KV_ + kvh) * S_ * HD_;
    const size_t vbase = (size_t)(b * KV_ + kvh) * HD_ * S_;
    const int srow0 = qt * 128 + w * 16 + q4 * 4;

    const int kt_lo = (2 * qt - 8) > 0 ? (2 * qt - 8) : 0;
    const int kt_hi = 2 * qt + 1;
    const int s_lo_w = qt * 128 + w * 16;
    int ktw_lo = (s_lo_w - (WINDOW_ - 1)) >> 6;
    if (ktw_lo < kt_lo) ktw_lo = kt_lo;
    const int ktw_hi = (s_lo_w + 15) >> 6;

    auto stage = [&](int kt, int buf) {
#pragma unroll
        for (int c = 0; c < 4; ++c) {
            const int chunk = w * 4 + c;
            const int keyl = chunk * 2 + (lane >> 5);
            const int g = (lane & 31) ^ (keyl & 31);
            GLOAD_LDS16(Kh + kbase + (size_t)(kt * 64 + keyl) * HD_ + g * 8,
                        sK[buf] + chunk * 512 + lane * 8);
            const int diml = chunk * 8 + (lane >> 3);
            const int g2 = (lane & 7) ^ (diml & 7);
            GLOAD_LDS16(Vt + vbase + (size_t)diml * S_ + kt * 64 + g2 * 8,
                        sV[buf] + chunk * 512 + lane * 8);
        }
    };

    stage(kt_lo, 0);
    int cur = 0;
    for (int kt = kt_lo; kt <= kt_hi; ++kt, cur ^= 1) {
        __syncthreads();
        if (kt < kt_hi) stage(kt + 1, cur ^ 1);
        if (kt < ktw_lo || kt > ktw_hi) continue;

        const f16* sKc = sK[cur];
        const f16* sVc = sV[cur];

        floatx4 sc[4];
#pragma unroll
        for (int nt = 0; nt < 4; ++nt) sc[nt] = (floatx4){0.f, 0.f, 0.f, 0.f};
#pragma unroll
        for (int ks = 0; ks < 8; ++ks)
#pragma unroll
            for (int nt = 0; nt < 4; ++nt) {
                const int keyl = nt * 16 + i16;
                const int gp = (ks * 4 + q4) ^ (keyl & 31);
                half8 kf = *(const half8*)(sKc + keyl * 256 + gp * 8);
                sc[nt] = __builtin_amdgcn_mfma_f32_16x16x32_f16(qf[ks], kf, sc[nt], 0, 0, 0);
            }

#pragma unroll
        for (int r = 0; r < 4; ++r) {
            const int s = srow0 + r;
            float mx = -1e30f;
#pragma unroll
            for (int nt = 0; nt < 4; ++nt) {
                const int j = kt * 64 + nt * 16 + i16;
                const bool valid = (j <= s) && (s - j < WINDOW_);
                const float v = valid ? sc[nt][r] : MASKV_;
                sc[nt][r] = v;
                mx = fmaxf(mx, v);
            }
#pragma unroll
            for (int off = 1; off < 16; off <<= 1) mx = fmaxf(mx, __shfl_xor(mx, off));
            const float mnew = fmaxf(mrow[r], mx);
            const float alpha = __expf(mrow[r] - mnew);
            mrow[r] = mnew;
            float rs = 0.f;
#pragma unroll
            for (int nt = 0; nt < 4; ++nt) {
                const float p = __expf(sc[nt][r] - mnew);
                sc[nt][r] = p;
                rs += p;
            }
#pragma unroll
            for (int off = 1; off < 16; off <<= 1) rs += __shfl_xor(rs, off);
            lrow[r] = lrow[r] * alpha + rs;
#pragma unroll
            for (int nt2 = 0; nt2 < 16; ++nt2) o[nt2][r] *= alpha;
        }

        f16* sPw = sP[w];
#pragma unroll
        for (int nt = 0; nt < 4; ++nt)
#pragma unroll
            for (int r = 0; r < 4; ++r)
                sPw[(q4 * 4 + r) * 72 + nt * 16 + i16] = (f16)sc[nt][r];
        asm volatile("s_waitcnt lgkmcnt(0)" ::: "memory");

#pragma unroll
        for (int kt2 = 0; kt2 < 2; ++kt2) {
            half8 pf = *(const half8*)(sPw + i16 * 72 + kt2 * 32 + q4 * 8);
#pragma unroll
            for (int nt2 = 0; nt2 < 16; ++nt2) {
                const int dim = nt2 * 16 + i16;
                const int gp = (kt2 * 4 + q4) ^ (dim & 7);
                half8 vf = *(const half8*)(sVc + dim * 64 + gp * 8);
                o[nt2] = __builtin_amdgcn_mfma_f32_16x16x32_f16(pf, vf, o[nt2], 0, 0, 0);
            }
        }
    }

    float inv2[4];
#pragma unroll
    for (int r = 0; r < 4; ++r) inv2[r] = 1.0f / lrow[r];
    f16* ob = attnh + (size_t)(b * S_ + qt * 128 + w * 16) * (H_ * HD_) + h * HD_;
#pragma unroll
    for (int nt2 = 0; nt2 < 16; ++nt2)
#pragma unroll
        for (int r = 0; r < 4; ++r)
            ob[(size_t)(q4 * 4 + r) * (H_ * HD_) + nt2 * 16 + i16] =
                (f16)(o[nt2][r] * inv2[r]);
}

// ---------------------------------------------------------------------------
extern "C" void kernel_launch(void* const* d_in, const int* in_sizes, int n_in,
                              void* d_out, int out_size, void* d_ws, size_t ws_size,
                              hipStream_t stream) {
    const float* x    = (const float*)d_in[0];
    const float* cosb = (const float*)d_in[1];
    const float* sinb = (const float*)d_in[2];
    const float* wq = (const float*)d_in[4];
    const float* wk = (const float*)d_in[5];
    const float* wv = (const float*)d_in[6];
    const float* wo = (const float*)d_in[7];
    const float* qw = (const float*)d_in[8];
    const float* kw = (const float*)d_in[9];
    float* out = (float*)d_out;

    f16* ws = (f16*)d_ws;
    f16* xh    = ws;                       // 8388608 (aliased as attnh later)
    f16* BT    = xh + 8388608;             // 6291456  [3072][2048]
    f16* woT   = BT + 6291456;             // 4194304  [2048][2048]
    f16* QKVh  = woT + 4194304;            // 12582912 [4096][3072]
    f16* Kh    = QKVh + 12582912;          // 2097152
    f16* Vt    = Kh + 2097152;             // 2097152
    f16* attnh = xh;                       // alias: xh dead after QKV GEMM

    const int M = B_ * S_;  // 4096

    // 1) convert x + transpose all weights (one dispatch)
    prep<<<8192 + 2560, 256, 0, stream>>>(x, wq, wk, wv, wo, xh, BT, woT);

    // 2) fused QKV projection: [4096][2048] @ [3072][2048]^T
    //    256x256 tile, ring-of-3, counted vmcnt.  grid 12x16 = 192 blocks.
    gemm_ring<256, 8, f16><<<dim3(12, 16), 512, 0, stream>>>(xh, BT, QKVh, M, 3072, D_);

    // 3) K norm+rope -> Kh, V norm+transpose -> Vt (Q fused into attn)
    norm_kv_f16<<<NRBK_ + 128, 256, 0, stream>>>(QKVh, Kh, Vt, cosb, sinb, kw);

    // 4) flash attention (fused Q norm+rope, double-buffered staging)
    attn_mfma<<<dim3(S_ / 128, H_, B_), 512, 0, stream>>>(QKVh, Kh, Vt, attnh,
                                                          cosb, sinb, qw);

    // 5) output projection: 256x128 tile, 4 waves, 2 blocks/CU.
    //    grid 16x16 = 256 blocks (vs 128 half-idle at 256x256).
    gemm_ring<128, 4, float><<<dim3(16, 16), 256, 0, stream>>>(attnh, woT, out,
                                                               M, D_, H_ * HD_);
}

// Round 2
// 313.694 us; speedup vs baseline: 1.2404x; 1.2404x over previous
//
#include <hip/hip_runtime.h>
#include <hip/hip_bf16.h>
#include <hip/hip_fp16.h>
#include <type_traits>

#define B_ 2
#define S_ 2048
#define D_ 2048
#define H_ 8
#define KV_ 2
#define HD_ 256
#define WINDOW_ 512
#define EPS_ 1e-6f
#define MASKV_ -30000.0f

typedef _Float16 f16;
typedef _Float16 half8 __attribute__((ext_vector_type(8)));
typedef _Float16 half2v __attribute__((ext_vector_type(2)));
typedef _Float16 half4v __attribute__((ext_vector_type(4)));
typedef float floatx4 __attribute__((ext_vector_type(4)));
typedef float floatx8 __attribute__((ext_vector_type(8)));
typedef float floatx16 __attribute__((ext_vector_type(16)));

#define GLOAD_LDS16(g, l)                                                        \
    __builtin_amdgcn_global_load_lds(                                            \
        (const __attribute__((address_space(1))) unsigned int*)(g),              \
        (__attribute__((address_space(3))) unsigned int*)(l), 16, 0, 0)

#define VMWAIT(n) asm volatile("s_waitcnt vmcnt(" #n ")" ::: "memory")
#define IC(n) std::integral_constant<int, n>{}

// ---------------------------------------------------------------------------
// prep: fp32->fp16 convert of x + all 4 weight transposes.  (round-0, proven)
// ---------------------------------------------------------------------------
__global__ __launch_bounds__(256) void prep(const float* __restrict__ x,
                                            const float* __restrict__ wq,
                                            const float* __restrict__ wk,
                                            const float* __restrict__ wv,
                                            const float* __restrict__ wo,
                                            f16* __restrict__ xh,
                                            f16* __restrict__ BT,
                                            f16* __restrict__ woT) {
    int bid = blockIdx.x;
    const int t = threadIdx.x;
    if (bid < 8192) {
        const int i = bid * 256 + t;
        float4 v = ((const float4*)x)[i];
        half4v hv = {(f16)v.x, (f16)v.y, (f16)v.z, (f16)v.w};
        ((half4v*)xh)[i] = hv;
        return;
    }
    bid -= 8192;
    const float* src;
    f16* dst;
    int C, bx, by;
    if (bid < 1024) {
        src = wq; dst = BT; C = 2048; bx = bid & 31; by = bid >> 5;
    } else if (bid < 1280) {
        const int b3 = bid - 1024;
        src = wk; dst = BT + (size_t)2048 * 2048; C = 512; bx = b3 & 7; by = b3 >> 3;
    } else if (bid < 1536) {
        const int b3 = bid - 1280;
        src = wv; dst = BT + (size_t)2560 * 2048; C = 512; bx = b3 & 7; by = b3 >> 3;
    } else {
        const int b3 = bid - 1536;
        src = wo; dst = woT; C = 2048; bx = b3 & 31; by = b3 >> 5;
    }
    __shared__ float tl[64][65];
    const int c0 = bx * 64, r0 = by * 64;
#pragma unroll
    for (int i = 0; i < 4; ++i) {
        const int idx = i * 256 + t;
        const int row = idx >> 4;
        const int c4 = (idx & 15) * 4;
        float4 v = *(const float4*)&src[(size_t)(r0 + row) * C + c0 + c4];
        tl[row][c4 + 0] = v.x; tl[row][c4 + 1] = v.y;
        tl[row][c4 + 2] = v.z; tl[row][c4 + 3] = v.w;
    }
    __syncthreads();
#pragma unroll
    for (int i = 0; i < 4; ++i) {
        const int idx = i * 256 + t;
        const int c = idx >> 4;
        const int r4 = (idx & 15) * 4;
        half4v hv = {(f16)tl[r4 + 0][c], (f16)tl[r4 + 1][c],
                     (f16)tl[r4 + 2][c], (f16)tl[r4 + 3][c]};
        *(half4v*)&dst[(size_t)(c0 + c) * 2048 + r0 + r4] = hv;
    }
}

// ---------------------------------------------------------------------------
// 2-phase fp16 MFMA GEMM (round-0, proven ~780 TF) — used for out-projection.
// ---------------------------------------------------------------------------
#define CH_ 528  // chunk stride in f16
template <typename OutT>
__global__ __launch_bounds__(256) void gemm_f16(const f16* __restrict__ A,
                                                const f16* __restrict__ BT,
                                                OutT* __restrict__ C,
                                                int M, int N, int K) {
    __shared__ __align__(16) f16 sA[16 * CH_];
    __shared__ __align__(16) f16 sB[16 * CH_];

    const int t = threadIdx.x;
    const int lane = t & 63;
    const int w = t >> 6;
    const int l31 = lane & 31, q1 = lane >> 5;
    const int m0 = blockIdx.y * 128, n0 = blockIdx.x * 128;
    const int mw = (w & 1) * 64, nw = (w >> 1) * 64;

    floatx16 acc[4];
#pragma unroll
    for (int i = 0; i < 4; ++i) acc[i] = (floatx16)(0.f);

    const int r8 = lane >> 3;
    const int g = (lane & 7) ^ r8;

    for (int k0 = 0; k0 < K; k0 += 64) {
#pragma unroll
        for (int cc = 0; cc < 4; ++cc) {
            const int chunk = w * 4 + cc;
            const int row = chunk * 8 + r8;
            GLOAD_LDS16(A + (size_t)(m0 + row) * K + k0 + g * 8,
                        sA + chunk * CH_ + lane * 8);
            GLOAD_LDS16(BT + (size_t)(n0 + row) * K + k0 + g * 8,
                        sB + chunk * CH_ + lane * 8);
        }
        __syncthreads();

#pragma unroll
        for (int ks = 0; ks < 4; ++ks) {
            const int G = ks * 2 + q1;
            half8 af[2], bf[2];
#pragma unroll
            for (int mt = 0; mt < 2; ++mt) {
                const int ra = mw + mt * 32 + l31;
                af[mt] = *(const half8*)(sA + (ra >> 3) * CH_ + (ra & 7) * 64 +
                                         (G ^ (ra & 7)) * 8);
                const int rb = nw + mt * 32 + l31;
                bf[mt] = *(const half8*)(sB + (rb >> 3) * CH_ + (rb & 7) * 64 +
                                         (G ^ (rb & 7)) * 8);
            }
#pragma unroll
            for (int mt = 0; mt < 2; ++mt)
#pragma unroll
                for (int nt = 0; nt < 2; ++nt)
                    acc[mt * 2 + nt] = __builtin_amdgcn_mfma_f32_32x32x16_f16(
                        af[mt], bf[nt], acc[mt * 2 + nt], 0, 0, 0);
        }
        __syncthreads();
    }

#pragma unroll
    for (int mt = 0; mt < 2; ++mt)
#pragma unroll
        for (int nt = 0; nt < 2; ++nt)
#pragma unroll
            for (int r = 0; r < 16; ++r) {
                const int row = m0 + mw + mt * 32 + (r & 3) + 8 * (r >> 2) + 4 * q1;
                const int col = n0 + nw + nt * 32 + l31;
                C[(size_t)row * N + col] = (OutT)acc[mt * 2 + nt][r];
            }
}

// ---------------------------------------------------------------------------
// 8-phase 256x256 MFMA GEMM (T2+T3+T4+T5), plain-HIP port of the verified
// template.  BK=64, 8 waves; per phase all waves compute ONE 128x128
// C-quadrant (qm=p&1, qn=p>>1) with 16x mfma_f32_16x16x32_f16 + 12x
// ds_read_b128, and stage ONE half-tile (order A0,B0,A1,B1 = first-use
// order of tile T+1).  Each operand half lives in a 4-slot ring
// (slot=(2T+h)&3): T+2 reuses T's slots, dead after T's phases -> staging
// T+1 during T is always slot-safe.
//
// vmcnt ledger (2 loads/staging), steady state entering T.ph{0,1,2}:
// outstanding = {<=4 tile-T stagings}+{issued T+1 so far}; vmcnt(4) leaves
// newest 2 stagings in flight and guarantees exactly the halves this phase
// reads; ph3 reads halves already guaranteed at ph1/ph2 -> no wait.
// Tail tile drains 4 -> 2 -> 0.  Barrier AFTER each wave's vmcnt transfers
// completion across waves.  Loads never drain to 0 in the main loop (T4).
//
// LDS swizzle (T2): halves are [128 rows][8 x 16B slots]; slot q of row r
// holds global k-slot q^(r&7) (pre-swizzled GLOBAL source, linear
// global_load_lds dest); reads use slot (ks*4+q4)^(i16&7) -> 2-way max.
// ---------------------------------------------------------------------------
template <typename OutT>
__global__ __launch_bounds__(512, 2) void gemm_8p(const f16* __restrict__ A,
                                                  const f16* __restrict__ BT,
                                                  OutT* __restrict__ C,
                                                  int M, int N, int K) {
    __shared__ __align__(16) f16 sAA[4 * 8192];  // 64 KB: 4 half-slots, 128x64
    __shared__ __align__(16) f16 sBB[4 * 8192];  // 64 KB

    const int tid = threadIdx.x;
    const int lane = tid & 63, w = tid >> 6;
    const int i16 = lane & 15, q4 = lane >> 4;
    const int w1 = w & 1, w2 = w >> 1;
    const int m0 = blockIdx.y * 256, n0 = blockIdx.x * 256;

    // staging: thread covers LDS bytes tid*16 and tid*16+8192 of a half.
    const int srow0 = tid >> 3;                          // + 64*i
    const int kx = ((tid & 7) ^ ((tid >> 3) & 7)) * 8;   // pre-swizzled src k
    const f16* srcA0 = A + (size_t)(m0 + srow0) * K;
    const f16* srcB0 = BT + (size_t)(n0 + srow0) * K;
    f16* dstA0 = sAA + tid * 8;
    f16* dstB0 = sBB + tid * 8;

    auto stage = [&](int P, int kt) {
        const int half = P >> 1;
        const int slot = (2 * kt + half) & 3;
        const int kb = kt * 64 + kx;
        if ((P & 1) == 0) {
            const f16* s = srcA0 + (size_t)(half * 128) * K + kb;
            f16* d = dstA0 + slot * 8192;
            GLOAD_LDS16(s, d);
            GLOAD_LDS16(s + (size_t)64 * K, d + 4096);
        } else {
            const f16* s = srcB0 + (size_t)(half * 128) * K + kb;
            f16* d = dstB0 + slot * 8192;
            GLOAD_LDS16(s, d);
            GLOAD_LDS16(s + (size_t)64 * K, d + 4096);
        }
    };

    // fragment-read offsets (f16 units)
    const int arow = (w1 * 64 + i16) * 64;
    const int brow = (w2 * 32 + i16) * 64;
    int xk[2];
    xk[0] = ((0 + q4) ^ (i16 & 7)) * 8;
    xk[1] = ((4 + q4) ^ (i16 & 7)) * 8;

    floatx4 acc[4][4][2];
#pragma unroll
    for (int p = 0; p < 4; ++p)
#pragma unroll
        for (int mt = 0; mt < 4; ++mt)
#pragma unroll
            for (int nt = 0; nt < 2; ++nt)
                acc[p][mt][nt] = (floatx4){0.f, 0.f, 0.f, 0.f};

    int st = 0;  // tile T's slot base: A-half h at st+h

    auto phase = [&](auto Pc, bool dostage, int ktn) {
        constexpr int P = decltype(Pc)::value;
        constexpr int qm = P & 1, qn = P >> 1;
        __builtin_amdgcn_s_barrier();
        const f16* ab = sAA + (size_t)(st + qm) * 8192;
        const f16* bb = sBB + (size_t)(st + qn) * 8192;
        half8 af[4][2], bf[2][2];
#pragma unroll
        for (int mt = 0; mt < 4; ++mt)
#pragma unroll
            for (int ks = 0; ks < 2; ++ks)
                af[mt][ks] = *(const half8*)(ab + arow + mt * 1024 + xk[ks]);
#pragma unroll
        for (int nt = 0; nt < 2; ++nt)
#pragma unroll
            for (int ks = 0; ks < 2; ++ks)
                bf[nt][ks] = *(const half8*)(bb + brow + nt * 1024 + xk[ks]);
        if (dostage) stage(P, ktn);
        __builtin_amdgcn_s_setprio(1);
#pragma unroll
        for (int mt = 0; mt < 4; ++mt)
#pragma unroll
            for (int nt = 0; nt < 2; ++nt)
#pragma unroll
                for (int ks = 0; ks < 2; ++ks)
                    acc[P][mt][nt] = __builtin_amdgcn_mfma_f32_16x16x32_f16(
                        af[mt][ks], bf[nt][ks], acc[P][mt][nt], 0, 0, 0);
        __builtin_amdgcn_s_setprio(0);
    };

    const int NT = K >> 6;  // K / 64

    // prologue: tile 0's four half-stagings in first-use order
    stage(0, 0); stage(1, 0); stage(2, 0); stage(3, 0);

    for (int T = 0; T < NT - 1; ++T) {
        VMWAIT(4); phase(IC(0), true, T + 1);
        VMWAIT(4); phase(IC(1), true, T + 1);
        VMWAIT(4); phase(IC(2), true, T + 1);
        phase(IC(3), true, T + 1);
        st ^= 2;
    }
    // tail tile: no staging; drain 4 -> 2 -> 0
    VMWAIT(4); phase(IC(0), false, 0);
    VMWAIT(2); phase(IC(1), false, 0);
    VMWAIT(0); phase(IC(2), false, 0);
    phase(IC(3), false, 0);

    // epilogue: C/D 16x16: row = q4*4 + reg, col = i16
#pragma unroll
    for (int p = 0; p < 4; ++p) {
        const int rb = m0 + (p & 1) * 128 + w1 * 64 + q4 * 4;
        const int cb = n0 + (p >> 1) * 128 + w2 * 32 + i16;
#pragma unroll
        for (int mt = 0; mt < 4; ++mt)
#pragma unroll
            for (int nt = 0; nt < 2; ++nt) {
                floatx4 v = acc[p][mt][nt];
#pragma unroll
                for (int r = 0; r < 4; ++r)
                    C[(size_t)(rb + mt * 16 + r) * N + cb + nt * 16] = (OutT)v[r];
            }
    }
}

// ---------------------------------------------------------------------------
// K/V norm kernel (round-0, proven).
// ---------------------------------------------------------------------------
#define NRBK_ ((B_ * S_ * KV_) / 4)  // 2048 blocks, 4 waves each

__global__ __launch_bounds__(256) void norm_kv_f16(
    const f16* __restrict__ QKVh, f16* __restrict__ Kh, f16* __restrict__ Vt,
    const float* __restrict__ cosb, const float* __restrict__ sinb,
    const float* __restrict__ kw) {
    __shared__ f16 vt[64][266];

    const int w = threadIdx.x >> 6, lane = threadIdx.x & 63;

    if (blockIdx.x < NRBK_) {
        const int wid = blockIdx.x * 4 + w;
        const int d0 = lane * 2;
        const int b = wid / (S_ * KV_);
        const int r = wid % (S_ * KV_);
        const int s = r / KV_, kv = r % KV_;
        const f16* p = QKVh + (size_t)(b * S_ + s) * 3072 + 2048 + kv * HD_;
        half2v lo = *(const half2v*)(p + d0);
        half2v hi = *(const half2v*)(p + 128 + d0);
        float x0 = (float)lo[0], x1 = (float)lo[1], x2 = (float)hi[0], x3 = (float)hi[1];
        float ss = x0 * x0 + x1 * x1 + x2 * x2 + x3 * x3;
#pragma unroll
        for (int off = 32; off >= 1; off >>= 1) ss += __shfl_xor(ss, off);
        const float inv = rsqrtf(ss * (1.0f / HD_) + EPS_);
        float2 wlo = *(const float2*)(kw + d0), whi = *(const float2*)(kw + 128 + d0);
        float y0 = x0 * inv * wlo.x, y1 = x1 * inv * wlo.y;
        float y2 = x2 * inv * whi.x, y3 = x3 * inv * whi.y;
        const float* cb = cosb + (size_t)(b * S_ + s) * HD_;
        const float* sb = sinb + (size_t)(b * S_ + s) * HD_;
        float2 clo = *(const float2*)(cb + d0), chi = *(const float2*)(cb + 128 + d0);
        float2 slo = *(const float2*)(sb + d0), shi = *(const float2*)(sb + 128 + d0);
        half2v olo = {(f16)(y0 * clo.x - y2 * slo.x), (f16)(y1 * clo.y - y3 * slo.y)};
        half2v ohi = {(f16)(y2 * chi.x + y0 * shi.x), (f16)(y3 * chi.y + y1 * shi.y)};
        f16* d = Kh + ((size_t)(b * KV_ + kv) * S_ + s) * HD_;
        *(half2v*)(d + d0) = olo;
        *(half2v*)(d + 128 + d0) = ohi;
        return;
    }

    const int vb = blockIdx.x - NRBK_;
    const int s0 = (vb & 31) * 64;
    const int kv = (vb >> 5) & 1;
    const int b  = vb >> 6;

    for (int r = 0; r < 16; ++r) {
        const int sl = w * 16 + r;
        const f16* p = QKVh + (size_t)(b * S_ + s0 + sl) * 3072 + 2560 + kv * HD_;
        const int d0 = lane * 2;
        half2v lo = *(const half2v*)(p + d0);
        half2v hi = *(const half2v*)(p + 128 + d0);
        float x0 = (float)lo[0], x1 = (float)lo[1], x2 = (float)hi[0], x3 = (float)hi[1];
        float ss = x0 * x0 + x1 * x1 + x2 * x2 + x3 * x3;
#pragma unroll
        for (int off = 32; off >= 1; off >>= 1) ss += __shfl_xor(ss, off);
        const float inv = rsqrtf(ss * (1.0f / HD_) + EPS_);
        half2v olo = {(f16)(x0 * inv), (f16)(x1 * inv)};
        half2v ohi = {(f16)(x2 * inv), (f16)(x3 * inv)};
        *(half2v*)&vt[sl][d0] = olo;
        *(half2v*)&vt[sl][128 + d0] = ohi;
    }
    __syncthreads();
    f16* dst = Vt + (size_t)(b * KV_ + kv) * HD_ * S_;
    for (int i = 0; i < 64; ++i) {
        const int dd = w * 64 + i;
        dst[(size_t)dd * S_ + s0 + lane] = vt[lane][dd];
    }
}

// ---------------------------------------------------------------------------
// MFMA flash attention (round-0, proven). 128 q, 8 waves, dbuf staging.
// ---------------------------------------------------------------------------
__global__ __launch_bounds__(512, 2) void attn_mfma(const f16* __restrict__ QKVh,
                                                    const f16* __restrict__ Kh,
                                                    const f16* __restrict__ Vt,
                                                    f16* __restrict__ attnh,
                                                    const float* __restrict__ cosb,
                                                    const float* __restrict__ sinb,
                                                    const float* __restrict__ qw) {
    __shared__ __align__(16) f16 sK[2][64 * 256];
    __shared__ __align__(16) f16 sV[2][256 * 64];
    __shared__ __align__(16) f16 sP[8][16 * 72];

    const int qt = blockIdx.x, h = blockIdx.y, b = blockIdx.z;
    const int kvh = h / (H_ / KV_);
    const int t = threadIdx.x, lane = t & 63, w = t >> 6;
    const int i16 = lane & 15, q4 = lane >> 4;

    const int qrow = qt * 128 + w * 16 + i16;
    const f16* qbase = QKVh + (size_t)(b * S_ + qrow) * 3072 + h * HD_ + q4 * 8;
    half8 qf[8];
#pragma unroll
    for (int kk = 0; kk < 8; ++kk) qf[kk] = *(const half8*)(qbase + kk * 32);

    {
        float ss = 0.f;
#pragma unroll
        for (int kk = 0; kk < 8; ++kk)
#pragma unroll
            for (int j = 0; j < 8; ++j) {
                const float v = (float)qf[kk][j];
                ss += v * v;
            }
        ss += __shfl_xor(ss, 16);
        ss += __shfl_xor(ss, 32);
        const float inv = rsqrtf(ss * (1.0f / HD_) + EPS_);
        const float* cb = cosb + (size_t)(b * S_ + qrow) * HD_ + q4 * 8;
        const float* sb = sinb + (size_t)(b * S_ + qrow) * HD_ + q4 * 8;
        const float* wp = qw + q4 * 8;
#pragma unroll
        for (int kk = 0; kk < 4; ++kk) {
            const int dl = kk * 32, dh = dl + 128;
            floatx8 cl = *(const floatx8*)(cb + dl);
            floatx8 ch = *(const floatx8*)(cb + dh);
            floatx8 sl = *(const floatx8*)(sb + dl);
            floatx8 sh = *(const floatx8*)(sb + dh);
            floatx8 wl = *(const floatx8*)(wp + dl);
            floatx8 wh = *(const floatx8*)(wp + dh);
            half8 nl, nh;
#pragma unroll
            for (int j = 0; j < 8; ++j) {
                const float xl = (float)qf[kk][j] * inv * wl[j];
                const float xh = (float)qf[kk + 4][j] * inv * wh[j];
                nl[j] = (f16)(xl * cl[j] - xh * sl[j]);
                nh[j] = (f16)(xh * ch[j] + xl * sh[j]);
            }
            qf[kk] = nl;
            qf[kk + 4] = nh;
        }
    }

    floatx4 o[16];
#pragma unroll
    for (int i = 0; i < 16; ++i) o[i] = (floatx4){0.f, 0.f, 0.f, 0.f};
    float mrow[4] = {-1e30f, -1e30f, -1e30f, -1e30f};
    float lrow[4] = {0.f, 0.f, 0.f, 0.f};

    const size_t kbase = (size_t)(b * KV_ + kvh) * S_ * HD_;
    const size_t vbase = (size_t)(b * KV_ + kvh) * HD_ * S_;
    const int srow0 = qt * 128 + w * 16 + q4 * 4;

    const int kt_lo = (2 * qt - 8) > 0 ? (2 * qt - 8) : 0;
    const int kt_hi = 2 * qt + 1;
    const int s_lo_w = qt * 128 + w * 16;
    int ktw_lo = (s_lo_w - (WINDOW_ - 1)) >> 6;
    if (ktw_lo < kt_lo) ktw_lo = kt_lo;
    const int ktw_hi = (s_lo_w + 15) >> 6;

    auto stage = [&](int kt, int buf) {
#pragma unroll
        for (int c = 0; c < 4; ++c) {
            const int chunk = w * 4 + c;
            const int keyl = chunk * 2 + (lane >> 5);
            const int g = (lane & 31) ^ (keyl & 31);
            GLOAD_LDS16(Kh + kbase + (size_t)(kt * 64 + keyl) * HD_ + g * 8,
                        sK[buf] + chunk * 512 + lane * 8);
            const int diml = chunk * 8 + (lane >> 3);
            const int g2 = (lane & 7) ^ (diml & 7);
            GLOAD_LDS16(Vt + vbase + (size_t)diml * S_ + kt * 64 + g2 * 8,
                        sV[buf] + chunk * 512 + lane * 8);
        }
    };

    stage(kt_lo, 0);
    int cur = 0;
    for (int kt = kt_lo; kt <= kt_hi; ++kt, cur ^= 1) {
        __syncthreads();
        if (kt < kt_hi) stage(kt + 1, cur ^ 1);
        if (kt < ktw_lo || kt > ktw_hi) continue;

        const f16* sKc = sK[cur];
        const f16* sVc = sV[cur];

        floatx4 sc[4];
#pragma unroll
        for (int nt = 0; nt < 4; ++nt) sc[nt] = (floatx4){0.f, 0.f, 0.f, 0.f};
#pragma unroll
        for (int ks = 0; ks < 8; ++ks)
#pragma unroll
            for (int nt = 0; nt < 4; ++nt) {
                const int keyl = nt * 16 + i16;
                const int gp = (ks * 4 + q4) ^ (keyl & 31);
                half8 kf = *(const half8*)(sKc + keyl * 256 + gp * 8);
                sc[nt] = __builtin_amdgcn_mfma_f32_16x16x32_f16(qf[ks], kf, sc[nt], 0, 0, 0);
            }

#pragma unroll
        for (int r = 0; r < 4; ++r) {
            const int s = srow0 + r;
            float mx = -1e30f;
#pragma unroll
            for (int nt = 0; nt < 4; ++nt) {
                const int j = kt * 64 + nt * 16 + i16;
                const bool valid = (j <= s) && (s - j < WINDOW_);
                const float v = valid ? sc[nt][r] : MASKV_;
                sc[nt][r] = v;
                mx = fmaxf(mx, v);
            }
#pragma unroll
            for (int off = 1; off < 16; off <<= 1) mx = fmaxf(mx, __shfl_xor(mx, off));
            const float mnew = fmaxf(mrow[r], mx);
            const float alpha = __expf(mrow[r] - mnew);
            mrow[r] = mnew;
            float rs = 0.f;
#pragma unroll
            for (int nt = 0; nt < 4; ++nt) {
                const float p = __expf(sc[nt][r] - mnew);
                sc[nt][r] = p;
                rs += p;
            }
#pragma unroll
            for (int off = 1; off < 16; off <<= 1) rs += __shfl_xor(rs, off);
            lrow[r] = lrow[r] * alpha + rs;
#pragma unroll
            for (int nt2 = 0; nt2 < 16; ++nt2) o[nt2][r] *= alpha;
        }

        f16* sPw = sP[w];
#pragma unroll
        for (int nt = 0; nt < 4; ++nt)
#pragma unroll
            for (int r = 0; r < 4; ++r)
                sPw[(q4 * 4 + r) * 72 + nt * 16 + i16] = (f16)sc[nt][r];
        asm volatile("s_waitcnt lgkmcnt(0)" ::: "memory");

#pragma unroll
        for (int kt2 = 0; kt2 < 2; ++kt2) {
            half8 pf = *(const half8*)(sPw + i16 * 72 + kt2 * 32 + q4 * 8);
#pragma unroll
            for (int nt2 = 0; nt2 < 16; ++nt2) {
                const int dim = nt2 * 16 + i16;
                const int gp = (kt2 * 4 + q4) ^ (dim & 7);
                half8 vf = *(const half8*)(sVc + dim * 64 + gp * 8);
                o[nt2] = __builtin_amdgcn_mfma_f32_16x16x32_f16(pf, vf, o[nt2], 0, 0, 0);
            }
        }
    }

    float inv2[4];
#pragma unroll
    for (int r = 0; r < 4; ++r) inv2[r] = 1.0f / lrow[r];
    f16* ob = attnh + (size_t)(b * S_ + qt * 128 + w * 16) * (H_ * HD_) + h * HD_;
#pragma unroll
    for (int nt2 = 0; nt2 < 16; ++nt2)
#pragma unroll
        for (int r = 0; r < 4; ++r)
            ob[(size_t)(q4 * 4 + r) * (H_ * HD_) + nt2 * 16 + i16] =
                (f16)(o[nt2][r] * inv2[r]);
}

// ---------------------------------------------------------------------------
extern "C" void kernel_launch(void* const* d_in, const int* in_sizes, int n_in,
                              void* d_out, int out_size, void* d_ws, size_t ws_size,
                              hipStream_t stream) {
    const float* x    = (const float*)d_in[0];
    const float* cosb = (const float*)d_in[1];
    const float* sinb = (const float*)d_in[2];
    const float* wq = (const float*)d_in[4];
    const float* wk = (const float*)d_in[5];
    const float* wv = (const float*)d_in[6];
    const float* wo = (const float*)d_in[7];
    const float* qw = (const float*)d_in[8];
    const float* kw = (const float*)d_in[9];
    float* out = (float*)d_out;

    f16* ws = (f16*)d_ws;
    f16* xh    = ws;                       // 8388608 (aliased as attnh later)
    f16* BT    = xh + 8388608;             // 6291456  [3072][2048]
    f16* woT   = BT + 6291456;             // 4194304  [2048][2048]
    f16* QKVh  = woT + 4194304;            // 12582912 [4096][3072]
    f16* Kh    = QKVh + 12582912;          // 2097152
    f16* Vt    = Kh + 2097152;             // 2097152
    f16* attnh = xh;                       // alias: xh dead after QKV GEMM

    const int M = B_ * S_;  // 4096

    // 1) convert x + transpose all weights (one dispatch)
    prep<<<8192 + 2560, 256, 0, stream>>>(x, wq, wk, wv, wo, xh, BT, woT);

    // 2) fused QKV projection: [4096][2048] @ [3072][2048]^T
    //    8-phase 256x256 template, counted vmcnt.  grid 12x16 = 192 blocks.
    gemm_8p<f16><<<dim3(12, 16), 512, 0, stream>>>(xh, BT, QKVh, M, 3072, D_);

    // 3) K norm+rope -> Kh, V norm+transpose -> Vt (Q fused into attn)
    norm_kv_f16<<<NRBK_ + 128, 256, 0, stream>>>(QKVh, Kh, Vt, cosb, sinb, kw);

    // 4) flash attention (fused Q norm+rope, double-buffered staging)
    attn_mfma<<<dim3(S_ / 128, H_, B_), 512, 0, stream>>>(QKVh, Kh, Vt, attnh,
                                                          cosb, sinb, qw);

    // 5) output projection (round-0 proven 2-phase 128x128, fp32 out)
    gemm_f16<float><<<dim3(16, 32), 256, 0, stream>>>(attnh, woT, out, M, D_, H_ * HD_);
}